// Round 2
// baseline (836.023 us; speedup 1.0000x reference)
//
#include <hip/hip_runtime.h>
#include <hip/hip_bf16.h>

#define NNODES 100000
#define NEDGES 1600000
#define ALPHA  0.2f
#define EPSV   1e-9f

// ---------------- zero scratch (row_sum, counts, cursor) ----------------
__global__ void k_zero(int* __restrict__ p, int n) {
    int i = blockIdx.x * blockDim.x + threadIdx.x;
    if (i < n) p[i] = 0;
}

// ---------------- f32 tiled GEMM: Wh = h @ W  [N,256]x[256,256] ----------------
__global__ __launch_bounds__(256) void k_gemm(const float* __restrict__ h,
                                              const float* __restrict__ W,
                                              float* __restrict__ Wh) {
    __shared__ float As[16][64];
    __shared__ float Bs[16][64];
    const int tid = threadIdx.x;
    const int m0 = blockIdx.x * 64;
    const int n0 = blockIdx.y * 64;
    const int tx = tid & 15, ty = tid >> 4;
    const int arow  = tid >> 2;        // 0..63
    const int akoff = (tid & 3) * 4;   // 0,4,8,12
    const int brow  = tid >> 4;        // 0..15
    const int bcol  = (tid & 15) * 4;  // 0..60
    float acc[4][4] = {};
    for (int k0 = 0; k0 < 256; k0 += 16) {
        float4 a = make_float4(0.f, 0.f, 0.f, 0.f);
        const int grow = m0 + arow;
        if (grow < NNODES)
            a = *(const float4*)&h[grow * 256 + k0 + akoff];
        const float4 b = *(const float4*)&W[(k0 + brow) * 256 + n0 + bcol];
        __syncthreads();   // protect previous iteration's LDS reads
        As[akoff + 0][arow] = a.x;
        As[akoff + 1][arow] = a.y;
        As[akoff + 2][arow] = a.z;
        As[akoff + 3][arow] = a.w;
        *(float4*)&Bs[brow][bcol] = b;
        __syncthreads();
#pragma unroll
        for (int kk = 0; kk < 16; ++kk) {
            float av[4], bv[4];
#pragma unroll
            for (int i = 0; i < 4; ++i) av[i] = As[kk][ty * 4 + i];
#pragma unroll
            for (int j = 0; j < 4; ++j) bv[j] = Bs[kk][tx * 4 + j];
#pragma unroll
            for (int i = 0; i < 4; ++i)
#pragma unroll
                for (int j = 0; j < 4; ++j)
                    acc[i][j] = fmaf(av[i], bv[j], acc[i][j]);
        }
    }
#pragma unroll
    for (int i = 0; i < 4; ++i) {
        const int row = m0 + ty * 4 + i;
        if (row < NNODES) {
            float4 o = make_float4(acc[i][0], acc[i][1], acc[i][2], acc[i][3]);
            *(float4*)&Wh[row * 256 + n0 + tx * 4] = o;
        }
    }
}

// ---------------- per-edge attention logits + row-sum + degree ----------------
__global__ void k_attn(const float* __restrict__ label,
                       const int* __restrict__ src,
                       const int* __restrict__ dst,
                       float* __restrict__ exp_e,
                       float* __restrict__ row_sum,
                       int* __restrict__ counts) {
    const int e = blockIdx.x * blockDim.x + threadIdx.x;
    if (e >= NEDGES) return;
    const int s = src[e], d = dst[e];
    const float4* ls = (const float4*)&label[s * 32];
    const float4* ld = (const float4*)&label[d * 32];
    float dot = 0.f;
#pragma unroll
    for (int i = 0; i < 8; ++i) {
        const float4 a = ls[i], b = ld[i];
        dot += a.x * b.x + a.y * b.y + a.z * b.z + a.w * b.w;
    }
    const float lr = dot >= 0.f ? dot : ALPHA * dot;
    const float ex = expf(lr);
    exp_e[e] = ex;
    atomicAdd(&row_sum[s], ex);
    atomicAdd(&counts[s], 1);
}

// ---------------- exclusive scan of counts -> row_start (3 kernels) ----------------
__global__ __launch_bounds__(256) void k_scan1(const int* __restrict__ counts,
                                               int* __restrict__ row_start,
                                               int* __restrict__ blockSums) {
    __shared__ int ssum[256];
    const int tid = threadIdx.x;
    const int base = blockIdx.x * 1024 + tid * 4;
    int v[4];
#pragma unroll
    for (int c = 0; c < 4; ++c) v[c] = (base + c < NNODES) ? counts[base + c] : 0;
    const int s = v[0] + v[1] + v[2] + v[3];
    ssum[tid] = s;
    __syncthreads();
    for (int off = 1; off < 256; off <<= 1) {
        const int t = (tid >= off) ? ssum[tid - off] : 0;
        __syncthreads();
        ssum[tid] += t;
        __syncthreads();
    }
    if (tid == 255) blockSums[blockIdx.x] = ssum[255];
    int p = ssum[tid] - s;   // exclusive within block
#pragma unroll
    for (int c = 0; c < 4; ++c) {
        if (base + c < NNODES) row_start[base + c] = p;
        p += v[c];
    }
}

__global__ __launch_bounds__(256) void k_scan2(int* __restrict__ blockSums, int nb) {
    __shared__ int ssum[256];
    const int tid = threadIdx.x;
    const int s = (tid < nb) ? blockSums[tid] : 0;
    ssum[tid] = s;
    __syncthreads();
    for (int off = 1; off < 256; off <<= 1) {
        const int t = (tid >= off) ? ssum[tid - off] : 0;
        __syncthreads();
        ssum[tid] += t;
        __syncthreads();
    }
    if (tid < nb) blockSums[tid] = ssum[tid] - s;  // exclusive
}

__global__ void k_scan3(int* __restrict__ row_start, const int* __restrict__ blockSums) {
    const int i = blockIdx.x * blockDim.x + threadIdx.x;
    if (i < NNODES) row_start[i] += blockSums[i >> 10];
}

// ---------------- scatter edges into CSR order, with normalized weights ----------------
__global__ void k_scatter(const int* __restrict__ src,
                          const int* __restrict__ dst,
                          const float* __restrict__ exp_e,
                          const float* __restrict__ row_sum,
                          const int* __restrict__ row_start,
                          int* __restrict__ cursor,
                          int* __restrict__ sorted_dst,
                          float* __restrict__ sorted_w) {
    const int e = blockIdx.x * blockDim.x + threadIdx.x;
    if (e >= NEDGES) return;
    const int s = src[e];
    const int pos = row_start[s] + atomicAdd(&cursor[s], 1);
    float rs = row_sum[s];
    rs = rs > EPSV ? rs : EPSV;
    sorted_dst[pos] = dst[e];
    sorted_w[pos] = exp_e[e] / rs;
}

// ---------------- per-node aggregation: one wave per node ----------------
__global__ __launch_bounds__(256) void k_aggregate(const float* __restrict__ Wh,
                                                   const int* __restrict__ row_start,
                                                   const int* __restrict__ sorted_dst,
                                                   const float* __restrict__ sorted_w,
                                                   float* __restrict__ out) {
    const int node = blockIdx.x * 4 + (threadIdx.x >> 6);
    if (node >= NNODES) return;
    const int lane = threadIdx.x & 63;
    const int rs = row_start[node];
    const int re = (node == NNODES - 1) ? NEDGES : row_start[node + 1];
    float4 acc = make_float4(0.f, 0.f, 0.f, 0.f);
    for (int i = rs; i < re; ++i) {
        const int d = sorted_dst[i];
        const float w = sorted_w[i];
        const float4 v = *(const float4*)&Wh[d * 256 + lane * 4];
        acc.x = fmaf(w, v.x, acc.x);
        acc.y = fmaf(w, v.y, acc.y);
        acc.z = fmaf(w, v.z, acc.z);
        acc.w = fmaf(w, v.w, acc.w);
    }
    *(float4*)&out[node * 256 + lane * 4] = acc;
}

extern "C" void kernel_launch(void* const* d_in, const int* in_sizes, int n_in,
                              void* d_out, int out_size, void* d_ws, size_t ws_size,
                              hipStream_t stream) {
    const float* h     = (const float*)d_in[0];   // [N,256]
    const float* label = (const float*)d_in[1];   // [N,32]
    const float* W     = (const float*)d_in[2];   // [256,256]
    const int*   adj   = (const int*)d_in[3];     // [2,E] (int32 per harness)
    const int* src = adj;
    const int* dst = adj + NEDGES;
    float* out = (float*)d_out;

    // workspace layout (bytes), all 16B-aligned.
    // NOTE: no trailing backslashes in these comments (line-continuation bug in R0!)
    char* ws = (char*)d_ws;
    float* Wh         = (float*)(ws + 0);            // N*256*4 = 102,400,000
    float* exp_e      = (float*)(ws + 102400000);    // E*4
    float* sorted_w   = (float*)(ws + 108800000);    // E*4
    int*   sorted_dst = (int*)  (ws + 115200000);    // E*4
    float* row_sum    = (float*)(ws + 121600000);    // N*4 -- contiguous with next two,
    int*   counts     = (int*)  (ws + 122000000);    // N*4 -- zeroed together as 3*N ints
    int*   cursor     = (int*)  (ws + 122400000);    // N*4
    int*   row_start  = (int*)  (ws + 122800000);    // N*4
    int*   blockSums  = (int*)  (ws + 123200000);    // 1024*4

    // zero row_sum + counts + cursor (3*N ints, contiguous)
    k_zero<<<(3 * NNODES + 255) / 256, 256, 0, stream>>>((int*)row_sum, 3 * NNODES);

    dim3 gg((NNODES + 63) / 64, 4);
    k_gemm<<<gg, 256, 0, stream>>>(h, W, Wh);

    k_attn<<<(NEDGES + 255) / 256, 256, 0, stream>>>(label, src, dst, exp_e, row_sum, counts);

    const int nb = (NNODES + 1023) / 1024;  // 98
    k_scan1<<<nb, 256, 0, stream>>>(counts, row_start, blockSums);
    k_scan2<<<1, 256, 0, stream>>>(blockSums, nb);
    k_scan3<<<(NNODES + 255) / 256, 256, 0, stream>>>(row_start, blockSums);

    k_scatter<<<(NEDGES + 255) / 256, 256, 0, stream>>>(src, dst, exp_e, row_sum,
                                                        row_start, cursor, sorted_dst, sorted_w);

    k_aggregate<<<(NNODES + 3) / 4, 256, 0, stream>>>(Wh, row_start, sorted_dst, sorted_w, out);
}

// Round 3
// 517.110 us; speedup vs baseline: 1.6167x; 1.6167x over previous
//
#include <hip/hip_runtime.h>
#include <hip/hip_bf16.h>

#define NNODES 100000
#define NEDGES 1600000
#define ALPHA  0.2f
#define EPSV   1e-9f

typedef __bf16 bf16x8 __attribute__((ext_vector_type(8)));
typedef float  f32x4  __attribute__((ext_vector_type(4)));
typedef unsigned short u16x8 __attribute__((ext_vector_type(8)));

// manual RNE f32 -> bf16 bits (avoids header-type surprises)
static __device__ inline unsigned short f2bf(float f) {
    unsigned int u = __float_as_uint(f);
    unsigned int r = u + 0x7fff + ((u >> 16) & 1);
    return (unsigned short)(r >> 16);
}
static __device__ inline float bf2f(unsigned short v) {
    return __uint_as_float((unsigned int)v << 16);
}

// ---------------- zero counts ----------------
__global__ void k_zero(int* __restrict__ p, int n) {
    int i = blockIdx.x * blockDim.x + threadIdx.x;
    if (i < n) p[i] = 0;
}

// ---------------- W [256][256] f32 -> Wt [n][k] bf16 (transposed) ----------------
__global__ void k_prepw(const float* __restrict__ W, unsigned short* __restrict__ Wt) {
    const int i = blockIdx.x * 256 + threadIdx.x;  // i = n*256 + k
    const int n = i >> 8, k = i & 255;
    Wt[i] = f2bf(W[k * 256 + n]);
}

// ---------------- bf16 MFMA GEMM: Wh[bf16] = h @ W ----------------
// BM=128, BN=256 (full N), BK=32. 256 threads = 4 waves; wave computes 64x128.
#define BM 128
#define BK 32
#define LSTRIDE 40   // ushorts per LDS row (32 + 8 pad) -> 80 B, breaks pow2 banks
__global__ __launch_bounds__(256, 2) void k_gemm(const float* __restrict__ h,
                                                 const unsigned short* __restrict__ Wt,
                                                 unsigned short* __restrict__ Wh) {
    __shared__ __align__(16) unsigned short As[BM * LSTRIDE];   // 10240 B
    __shared__ __align__(16) unsigned short Bs[256 * LSTRIDE];  // 20480 B
    const int tid  = threadIdx.x;
    const int m0   = blockIdx.x * BM;
    const int wave = tid >> 6;
    const int lane = tid & 63;
    const int wm = (wave & 1) * 64;    // wave row offset in tile
    const int wn = (wave >> 1) * 128;  // wave col offset
    const int fm = lane & 15;          // fragment row/col
    const int fq = lane >> 4;          // quad id
    const int fk = fq * 8;             // fragment k offset

    f32x4 acc[4][8];
    const f32x4 z = {0.f, 0.f, 0.f, 0.f};
#pragma unroll
    for (int i = 0; i < 4; ++i)
#pragma unroll
        for (int j = 0; j < 8; ++j) acc[i][j] = z;

    const int arow = tid >> 1;          // 0..127
    const int acol = (tid & 1) * 16;    // 0 or 16 (floats)
    const bool arow_ok = (m0 + arow) < NNODES;
    const float* hrow = h + (size_t)(m0 + arow) * 256 + acol;

    for (int kc = 0; kc < 256; kc += BK) {
        // ---- global loads (A: f32, converted; B: pre-cast bf16) ----
        float4 a0, a1, a2, a3;
        if (arow_ok) {
            a0 = *(const float4*)(hrow + kc + 0);
            a1 = *(const float4*)(hrow + kc + 4);
            a2 = *(const float4*)(hrow + kc + 8);
            a3 = *(const float4*)(hrow + kc + 12);
        } else {
            a0 = a1 = a2 = a3 = make_float4(0.f, 0.f, 0.f, 0.f);
        }
        u16x8 bv[4];
#pragma unroll
        for (int q = 0; q < 4; ++q) {
            const int c = tid + 256 * q;        // chunk id, 0..1023
            const int n = c >> 2, koff = (c & 3) * 8;
            bv[q] = *(const u16x8*)(Wt + n * 256 + kc + koff);
        }
        __syncthreads();  // previous iteration finished reading LDS
        u16x8 p0, p1;
        p0[0]=f2bf(a0.x); p0[1]=f2bf(a0.y); p0[2]=f2bf(a0.z); p0[3]=f2bf(a0.w);
        p0[4]=f2bf(a1.x); p0[5]=f2bf(a1.y); p0[6]=f2bf(a1.z); p0[7]=f2bf(a1.w);
        p1[0]=f2bf(a2.x); p1[1]=f2bf(a2.y); p1[2]=f2bf(a2.z); p1[3]=f2bf(a2.w);
        p1[4]=f2bf(a3.x); p1[5]=f2bf(a3.y); p1[6]=f2bf(a3.z); p1[7]=f2bf(a3.w);
        *(u16x8*)&As[arow * LSTRIDE + acol]     = p0;
        *(u16x8*)&As[arow * LSTRIDE + acol + 8] = p1;
#pragma unroll
        for (int q = 0; q < 4; ++q) {
            const int c = tid + 256 * q;
            const int n = c >> 2, koff = (c & 3) * 8;
            *(u16x8*)&Bs[n * LSTRIDE + koff] = bv[q];
        }
        __syncthreads();  // staging visible
        // ---- fragments + MFMA ----
        bf16x8 af[4], bfr[8];
#pragma unroll
        for (int i = 0; i < 4; ++i)
            af[i] = __builtin_bit_cast(bf16x8,
                *(const u16x8*)&As[(wm + 16 * i + fm) * LSTRIDE + fk]);
#pragma unroll
        for (int j = 0; j < 8; ++j)
            bfr[j] = __builtin_bit_cast(bf16x8,
                *(const u16x8*)&Bs[(wn + 16 * j + fm) * LSTRIDE + fk]);
#pragma unroll
        for (int i = 0; i < 4; ++i)
#pragma unroll
            for (int j = 0; j < 8; ++j)
                acc[i][j] = __builtin_amdgcn_mfma_f32_16x16x32_bf16(af[i], bfr[j], acc[i][j], 0, 0, 0);
    }
    // ---- epilogue: C/D mapping col=lane&15, row=quad*4+reg ----
#pragma unroll
    for (int i = 0; i < 4; ++i) {
#pragma unroll
        for (int r = 0; r < 4; ++r) {
            const int grow = m0 + wm + 16 * i + fq * 4 + r;
            if (grow < NNODES) {
                unsigned short* orow = Wh + (size_t)grow * 256 + wn + fm;
#pragma unroll
                for (int j = 0; j < 8; ++j)
                    orow[16 * j] = f2bf(acc[i][j][r]);
            }
        }
    }
}

// ---------------- per-edge attention: exp(leakyrelu(dot)) + CSR position ----------------
__global__ void k_attn(const float* __restrict__ label,
                       const int* __restrict__ src,
                       const int* __restrict__ dst,
                       float* __restrict__ exp_e,
                       int* __restrict__ pos_in_row,
                       int* __restrict__ counts) {
    const int e = blockIdx.x * blockDim.x + threadIdx.x;
    if (e >= NEDGES) return;
    const int s = src[e], d = dst[e];
    const float4* ls = (const float4*)&label[s * 32];
    const float4* ld = (const float4*)&label[d * 32];
    float dot = 0.f;
#pragma unroll
    for (int i = 0; i < 8; ++i) {
        const float4 a = ls[i], b = ld[i];
        dot += a.x * b.x + a.y * b.y + a.z * b.z + a.w * b.w;
    }
    const float lr = dot >= 0.f ? dot : ALPHA * dot;
    exp_e[e] = expf(lr);
    pos_in_row[e] = atomicAdd(&counts[s], 1);
}

// ---------------- exclusive scan of counts -> row_start ----------------
__global__ __launch_bounds__(256) void k_scan1(const int* __restrict__ counts,
                                               int* __restrict__ row_start,
                                               int* __restrict__ blockSums) {
    __shared__ int ssum[256];
    const int tid = threadIdx.x;
    const int base = blockIdx.x * 1024 + tid * 4;
    int v[4];
#pragma unroll
    for (int c = 0; c < 4; ++c) v[c] = (base + c < NNODES) ? counts[base + c] : 0;
    const int s = v[0] + v[1] + v[2] + v[3];
    ssum[tid] = s;
    __syncthreads();
    for (int off = 1; off < 256; off <<= 1) {
        const int t = (tid >= off) ? ssum[tid - off] : 0;
        __syncthreads();
        ssum[tid] += t;
        __syncthreads();
    }
    if (tid == 255) blockSums[blockIdx.x] = ssum[255];
    int p = ssum[tid] - s;
#pragma unroll
    for (int c = 0; c < 4; ++c) {
        if (base + c < NNODES) row_start[base + c] = p;
        p += v[c];
    }
}

__global__ __launch_bounds__(256) void k_scan2(int* __restrict__ blockSums, int nb) {
    __shared__ int ssum[256];
    const int tid = threadIdx.x;
    const int s = (tid < nb) ? blockSums[tid] : 0;
    ssum[tid] = s;
    __syncthreads();
    for (int off = 1; off < 256; off <<= 1) {
        const int t = (tid >= off) ? ssum[tid - off] : 0;
        __syncthreads();
        ssum[tid] += t;
        __syncthreads();
    }
    if (tid < nb) blockSums[tid] = ssum[tid] - s;
}

__global__ void k_scan3(int* __restrict__ row_start, const int* __restrict__ blockSums) {
    const int i = blockIdx.x * blockDim.x + threadIdx.x;
    if (i < NNODES) row_start[i] += blockSums[i >> 10];
}

// ---------------- scatter edges into CSR order (no atomics) ----------------
__global__ void k_scatter(const int* __restrict__ src,
                          const int* __restrict__ dst,
                          const float* __restrict__ exp_e,
                          const int* __restrict__ pos_in_row,
                          const int* __restrict__ row_start,
                          int* __restrict__ sorted_dst,
                          float* __restrict__ sorted_w) {
    const int e = blockIdx.x * blockDim.x + threadIdx.x;
    if (e >= NEDGES) return;
    const int pos = row_start[src[e]] + pos_in_row[e];
    sorted_dst[pos] = dst[e];
    sorted_w[pos] = exp_e[e];   // un-normalized; normalize in aggregate
}

// ---------------- per-node aggregation: one wave per node, bf16 Wh gathers ----------------
__global__ __launch_bounds__(256) void k_aggregate(const unsigned short* __restrict__ Wh,
                                                   const int* __restrict__ row_start,
                                                   const int* __restrict__ sorted_dst,
                                                   const float* __restrict__ sorted_w,
                                                   float* __restrict__ out) {
    const int node = blockIdx.x * 4 + (threadIdx.x >> 6);
    if (node >= NNODES) return;
    const int lane = threadIdx.x & 63;
    const int rs = row_start[node];
    const int re = (node == NNODES - 1) ? NEDGES : row_start[node + 1];
    float4 acc = make_float4(0.f, 0.f, 0.f, 0.f);
    float wsum = 0.f;
    for (int i = rs; i < re; ++i) {
        const int d = sorted_dst[i];
        const float w = sorted_w[i];
        wsum += w;
        const ushort4 v = *(const ushort4*)&Wh[(size_t)d * 256 + lane * 4];
        acc.x = fmaf(w, bf2f(v.x), acc.x);
        acc.y = fmaf(w, bf2f(v.y), acc.y);
        acc.z = fmaf(w, bf2f(v.z), acc.z);
        acc.w = fmaf(w, bf2f(v.w), acc.w);
    }
    const float inv = 1.f / fmaxf(wsum, EPSV);
    acc.x *= inv; acc.y *= inv; acc.z *= inv; acc.w *= inv;
    *(float4*)&out[(size_t)node * 256 + lane * 4] = acc;
}

extern "C" void kernel_launch(void* const* d_in, const int* in_sizes, int n_in,
                              void* d_out, int out_size, void* d_ws, size_t ws_size,
                              hipStream_t stream) {
    const float* h     = (const float*)d_in[0];   // [N,256]
    const float* label = (const float*)d_in[1];   // [N,32]
    const float* W     = (const float*)d_in[2];   // [256,256]
    const int*   adj   = (const int*)d_in[3];     // [2,E]
    const int* src = adj;
    const int* dst = adj + NEDGES;
    float* out = (float*)d_out;

    // workspace layout (bytes, 16B-aligned offsets; no trailing backslash comments)
    char* ws = (char*)d_ws;
    unsigned short* Wh  = (unsigned short*)(ws + 0);          // N*256*2 = 51,200,000
    unsigned short* Wt  = (unsigned short*)(ws + 51200000);   // 256*256*2 = 131,072
    float* exp_e        = (float*)(ws + 51400000);            // E*4
    int*   pos_in_row   = (int*)  (ws + 57800000);            // E*4
    float* sorted_w     = (float*)(ws + 64200000);            // E*4
    int*   sorted_dst   = (int*)  (ws + 70600000);            // E*4
    int*   counts       = (int*)  (ws + 77000000);            // N*4
    int*   row_start    = (int*)  (ws + 77400000);            // N*4
    int*   blockSums    = (int*)  (ws + 77800000);            // 1024*4

    k_zero<<<(NNODES + 255) / 256, 256, 0, stream>>>(counts, NNODES);
    k_prepw<<<256, 256, 0, stream>>>(W, Wt);
    k_gemm<<<(NNODES + BM - 1) / BM, 256, 0, stream>>>(h, Wt, Wh);
    k_attn<<<(NEDGES + 255) / 256, 256, 0, stream>>>(label, src, dst, exp_e, pos_in_row, counts);

    const int nb = (NNODES + 1023) / 1024;  // 98
    k_scan1<<<nb, 256, 0, stream>>>(counts, row_start, blockSums);
    k_scan2<<<1, 256, 0, stream>>>(blockSums, nb);
    k_scan3<<<(NNODES + 255) / 256, 256, 0, stream>>>(row_start, blockSums);

    k_scatter<<<(NEDGES + 255) / 256, 256, 0, stream>>>(src, dst, exp_e, pos_in_row,
                                                        row_start, sorted_dst, sorted_w);
    k_aggregate<<<(NNODES + 3) / 4, 256, 0, stream>>>(Wh, row_start, sorted_dst, sorted_w, out);
}

// Round 4
// 428.896 us; speedup vs baseline: 1.9492x; 1.2057x over previous
//
#include <hip/hip_runtime.h>
#include <hip/hip_bf16.h>

#define NNODES 100000
#define NEDGES 1600000
#define ALPHA  0.2f
#define EPSV   1e-9f

typedef __bf16 bf16x8 __attribute__((ext_vector_type(8)));
typedef float  f32x4  __attribute__((ext_vector_type(4)));
typedef unsigned short u16x8 __attribute__((ext_vector_type(8)));

// manual RNE f32 -> bf16 bits
static __device__ inline unsigned short f2bf(float f) {
    unsigned int u = __float_as_uint(f);
    unsigned int r = u + 0x7fff + ((u >> 16) & 1);
    return (unsigned short)(r >> 16);
}
static __device__ inline float bf2f(unsigned short v) {
    return __uint_as_float((unsigned int)v << 16);
}

// ---------------- zero counts ----------------
__global__ void k_zero(int* __restrict__ p, int n) {
    int i = blockIdx.x * blockDim.x + threadIdx.x;
    if (i < n) p[i] = 0;
}

// ---------------- W [256][256] f32 -> Wt [n][k] bf16 (transposed) ----------------
__global__ void k_prepw(const float* __restrict__ W, unsigned short* __restrict__ Wt) {
    const int i = blockIdx.x * 256 + threadIdx.x;  // i = n*256 + k
    const int n = i >> 8, k = i & 255;
    Wt[i] = f2bf(W[k * 256 + n]);
}

// ---------------- bf16 MFMA GEMM: Wh[bf16] = h @ W (unchanged from R3) ----------------
#define BM 128
#define BK 32
#define LSTRIDE 40
__global__ __launch_bounds__(256, 2) void k_gemm(const float* __restrict__ h,
                                                 const unsigned short* __restrict__ Wt,
                                                 unsigned short* __restrict__ Wh) {
    __shared__ __align__(16) unsigned short As[BM * LSTRIDE];
    __shared__ __align__(16) unsigned short Bs[256 * LSTRIDE];
    const int tid  = threadIdx.x;
    const int m0   = blockIdx.x * BM;
    const int wave = tid >> 6;
    const int lane = tid & 63;
    const int wm = (wave & 1) * 64;
    const int wn = (wave >> 1) * 128;
    const int fm = lane & 15;
    const int fq = lane >> 4;
    const int fk = fq * 8;

    f32x4 acc[4][8];
    const f32x4 z = {0.f, 0.f, 0.f, 0.f};
#pragma unroll
    for (int i = 0; i < 4; ++i)
#pragma unroll
        for (int j = 0; j < 8; ++j) acc[i][j] = z;

    const int arow = tid >> 1;
    const int acol = (tid & 1) * 16;
    const bool arow_ok = (m0 + arow) < NNODES;
    const float* hrow = h + (size_t)(m0 + arow) * 256 + acol;

    for (int kc = 0; kc < 256; kc += BK) {
        float4 a0, a1, a2, a3;
        if (arow_ok) {
            a0 = *(const float4*)(hrow + kc + 0);
            a1 = *(const float4*)(hrow + kc + 4);
            a2 = *(const float4*)(hrow + kc + 8);
            a3 = *(const float4*)(hrow + kc + 12);
        } else {
            a0 = a1 = a2 = a3 = make_float4(0.f, 0.f, 0.f, 0.f);
        }
        u16x8 bv[4];
#pragma unroll
        for (int q = 0; q < 4; ++q) {
            const int c = tid + 256 * q;
            const int n = c >> 2, koff = (c & 3) * 8;
            bv[q] = *(const u16x8*)(Wt + n * 256 + kc + koff);
        }
        __syncthreads();
        u16x8 p0, p1;
        p0[0]=f2bf(a0.x); p0[1]=f2bf(a0.y); p0[2]=f2bf(a0.z); p0[3]=f2bf(a0.w);
        p0[4]=f2bf(a1.x); p0[5]=f2bf(a1.y); p0[6]=f2bf(a1.z); p0[7]=f2bf(a1.w);
        p1[0]=f2bf(a2.x); p1[1]=f2bf(a2.y); p1[2]=f2bf(a2.z); p1[3]=f2bf(a2.w);
        p1[4]=f2bf(a3.x); p1[5]=f2bf(a3.y); p1[6]=f2bf(a3.z); p1[7]=f2bf(a3.w);
        *(u16x8*)&As[arow * LSTRIDE + acol]     = p0;
        *(u16x8*)&As[arow * LSTRIDE + acol + 8] = p1;
#pragma unroll
        for (int q = 0; q < 4; ++q) {
            const int c = tid + 256 * q;
            const int n = c >> 2, koff = (c & 3) * 8;
            *(u16x8*)&Bs[n * LSTRIDE + koff] = bv[q];
        }
        __syncthreads();
        bf16x8 af[4], bfr[8];
#pragma unroll
        for (int i = 0; i < 4; ++i)
            af[i] = __builtin_bit_cast(bf16x8,
                *(const u16x8*)&As[(wm + 16 * i + fm) * LSTRIDE + fk]);
#pragma unroll
        for (int j = 0; j < 8; ++j)
            bfr[j] = __builtin_bit_cast(bf16x8,
                *(const u16x8*)&Bs[(wn + 16 * j + fm) * LSTRIDE + fk]);
#pragma unroll
        for (int i = 0; i < 4; ++i)
#pragma unroll
            for (int j = 0; j < 8; ++j)
                acc[i][j] = __builtin_amdgcn_mfma_f32_16x16x32_bf16(af[i], bfr[j], acc[i][j], 0, 0, 0);
    }
#pragma unroll
    for (int i = 0; i < 4; ++i) {
#pragma unroll
        for (int r = 0; r < 4; ++r) {
            const int grow = m0 + wm + 16 * i + fq * 4 + r;
            if (grow < NNODES) {
                unsigned short* orow = Wh + (size_t)grow * 256 + wn + fm;
#pragma unroll
                for (int j = 0; j < 8; ++j)
                    orow[16 * j] = f2bf(acc[i][j][r]);
            }
        }
    }
}

// ---------------- attention: 4 lanes per edge, quad shuffle reduce ----------------
__global__ __launch_bounds__(256) void k_attn(const float* __restrict__ label,
                       const int* __restrict__ src,
                       const int* __restrict__ dst,
                       float* __restrict__ exp_e,
                       int* __restrict__ pos_in_row,
                       int* __restrict__ counts) {
    const int t = blockIdx.x * 256 + threadIdx.x;
    const int e = t >> 2;            // edge id
    const int l4 = t & 3;            // lane within quad
    if (e >= NEDGES) return;
    const int s = src[e], d = dst[e];
    const float4* ls = (const float4*)&label[s * 32 + l4 * 8];
    const float4* ld = (const float4*)&label[d * 32 + l4 * 8];
    const float4 a0 = ls[0], a1 = ls[1];
    const float4 b0 = ld[0], b1 = ld[1];
    float dot = a0.x * b0.x + a0.y * b0.y + a0.z * b0.z + a0.w * b0.w
              + a1.x * b1.x + a1.y * b1.y + a1.z * b1.z + a1.w * b1.w;
    dot += __shfl_xor(dot, 1);
    dot += __shfl_xor(dot, 2);
    if (l4 == 0) {
        const float lr = dot >= 0.f ? dot : ALPHA * dot;
        exp_e[e] = expf(lr);
        pos_in_row[e] = atomicAdd(&counts[s], 1);
    }
}

// ---------------- exclusive scan of counts -> row_start ----------------
__global__ __launch_bounds__(256) void k_scan1(const int* __restrict__ counts,
                                               int* __restrict__ row_start,
                                               int* __restrict__ blockSums) {
    __shared__ int ssum[256];
    const int tid = threadIdx.x;
    const int base = blockIdx.x * 1024 + tid * 4;
    int v[4];
#pragma unroll
    for (int c = 0; c < 4; ++c) v[c] = (base + c < NNODES) ? counts[base + c] : 0;
    const int s = v[0] + v[1] + v[2] + v[3];
    ssum[tid] = s;
    __syncthreads();
    for (int off = 1; off < 256; off <<= 1) {
        const int t = (tid >= off) ? ssum[tid - off] : 0;
        __syncthreads();
        ssum[tid] += t;
        __syncthreads();
    }
    if (tid == 255) blockSums[blockIdx.x] = ssum[255];
    int p = ssum[tid] - s;
#pragma unroll
    for (int c = 0; c < 4; ++c) {
        if (base + c < NNODES) row_start[base + c] = p;
        p += v[c];
    }
}

__global__ __launch_bounds__(256) void k_scan2(int* __restrict__ blockSums, int nb) {
    __shared__ int ssum[256];
    const int tid = threadIdx.x;
    const int s = (tid < nb) ? blockSums[tid] : 0;
    ssum[tid] = s;
    __syncthreads();
    for (int off = 1; off < 256; off <<= 1) {
        const int t = (tid >= off) ? ssum[tid - off] : 0;
        __syncthreads();
        ssum[tid] += t;
        __syncthreads();
    }
    if (tid < nb) blockSums[tid] = ssum[tid] - s;
}

__global__ void k_scan3(int* __restrict__ row_start, const int* __restrict__ blockSums) {
    const int i = blockIdx.x * blockDim.x + threadIdx.x;
    if (i < NNODES) row_start[i] += blockSums[i >> 10];
}

// ---------------- scatter edges into CSR order, packed (dst, w) ----------------
__global__ void k_scatter(const int* __restrict__ src,
                          const int* __restrict__ dst,
                          const float* __restrict__ exp_e,
                          const int* __restrict__ pos_in_row,
                          const int* __restrict__ row_start,
                          uint2* __restrict__ sorted_pack) {
    const int e = blockIdx.x * blockDim.x + threadIdx.x;
    if (e >= NEDGES) return;
    const int pos = row_start[src[e]] + pos_in_row[e];
    sorted_pack[pos] = make_uint2((unsigned)dst[e], __float_as_uint(exp_e[e]));
}

// ---------------- aggregation: 32 lanes/node, 16B gathers, x4 unroll ----------------
__global__ __launch_bounds__(256) void k_aggregate(const unsigned short* __restrict__ Wh,
                                                   const int* __restrict__ row_start,
                                                   const uint2* __restrict__ sorted_pack,
                                                   float* __restrict__ out) {
    const int node = blockIdx.x * 8 + (threadIdx.x >> 5);
    if (node >= NNODES) return;
    const int sub = threadIdx.x & 31;      // owns channels [sub*8, sub*8+8)
    const int rs = row_start[node];
    const int re = (node == NNODES - 1) ? NEDGES : row_start[node + 1];
    const unsigned short* __restrict__ Whc = Wh + sub * 8;
    float acc[8] = {0.f, 0.f, 0.f, 0.f, 0.f, 0.f, 0.f, 0.f};
    float wsum = 0.f;
    int i = rs;
    for (; i + 4 <= re; i += 4) {
        const uint2 p0 = sorted_pack[i + 0];
        const uint2 p1 = sorted_pack[i + 1];
        const uint2 p2 = sorted_pack[i + 2];
        const uint2 p3 = sorted_pack[i + 3];
        const u16x8 v0 = *(const u16x8*)&Whc[(size_t)p0.x * 256];
        const u16x8 v1 = *(const u16x8*)&Whc[(size_t)p1.x * 256];
        const u16x8 v2 = *(const u16x8*)&Whc[(size_t)p2.x * 256];
        const u16x8 v3 = *(const u16x8*)&Whc[(size_t)p3.x * 256];
        const float w0 = __uint_as_float(p0.y), w1 = __uint_as_float(p1.y);
        const float w2 = __uint_as_float(p2.y), w3 = __uint_as_float(p3.y);
        wsum += (w0 + w1) + (w2 + w3);
#pragma unroll
        for (int c = 0; c < 8; ++c) {
            acc[c] = fmaf(w0, bf2f(v0[c]), acc[c]);
            acc[c] = fmaf(w1, bf2f(v1[c]), acc[c]);
            acc[c] = fmaf(w2, bf2f(v2[c]), acc[c]);
            acc[c] = fmaf(w3, bf2f(v3[c]), acc[c]);
        }
    }
    for (; i < re; ++i) {
        const uint2 p = sorted_pack[i];
        const u16x8 v = *(const u16x8*)&Whc[(size_t)p.x * 256];
        const float w = __uint_as_float(p.y);
        wsum += w;
#pragma unroll
        for (int c = 0; c < 8; ++c) acc[c] = fmaf(w, bf2f(v[c]), acc[c]);
    }
    const float inv = 1.f / fmaxf(wsum, EPSV);
    float4 o0 = make_float4(acc[0] * inv, acc[1] * inv, acc[2] * inv, acc[3] * inv);
    float4 o1 = make_float4(acc[4] * inv, acc[5] * inv, acc[6] * inv, acc[7] * inv);
    float* orow = out + (size_t)node * 256 + sub * 8;
    *(float4*)(orow + 0) = o0;
    *(float4*)(orow + 4) = o1;
}

extern "C" void kernel_launch(void* const* d_in, const int* in_sizes, int n_in,
                              void* d_out, int out_size, void* d_ws, size_t ws_size,
                              hipStream_t stream) {
    const float* h     = (const float*)d_in[0];   // [N,256]
    const float* label = (const float*)d_in[1];   // [N,32]
    const float* W     = (const float*)d_in[2];   // [256,256]
    const int*   adj   = (const int*)d_in[3];     // [2,E]
    const int* src = adj;
    const int* dst = adj + NEDGES;
    float* out = (float*)d_out;

    // workspace layout (bytes, 16B-aligned offsets; no trailing backslash comments)
    char* ws = (char*)d_ws;
    unsigned short* Wh  = (unsigned short*)(ws + 0);          // N*256*2 = 51,200,000
    unsigned short* Wt  = (unsigned short*)(ws + 51200000);   // 256*256*2
    float* exp_e        = (float*)(ws + 51400000);            // E*4
    int*   pos_in_row   = (int*)  (ws + 57800000);            // E*4
    uint2* sorted_pack  = (uint2*)(ws + 64200000);            // E*8
    int*   counts       = (int*)  (ws + 77000000);            // N*4
    int*   row_start    = (int*)  (ws + 77400000);            // N*4
    int*   blockSums    = (int*)  (ws + 77800000);            // 1024*4

    k_zero<<<(NNODES + 255) / 256, 256, 0, stream>>>(counts, NNODES);
    k_prepw<<<256, 256, 0, stream>>>(W, Wt);
    k_gemm<<<(NNODES + BM - 1) / BM, 256, 0, stream>>>(h, Wt, Wh);
    k_attn<<<(4 * NEDGES + 255) / 256, 256, 0, stream>>>(label, src, dst, exp_e, pos_in_row, counts);

    const int nb = (NNODES + 1023) / 1024;  // 98
    k_scan1<<<nb, 256, 0, stream>>>(counts, row_start, blockSums);
    k_scan2<<<1, 256, 0, stream>>>(blockSums, nb);
    k_scan3<<<(NNODES + 255) / 256, 256, 0, stream>>>(row_start, blockSums);

    k_scatter<<<(NEDGES + 255) / 256, 256, 0, stream>>>(src, dst, exp_e, pos_in_row,
                                                        row_start, sorted_pack);
    k_aggregate<<<(NNODES + 7) / 8, 256, 0, stream>>>(Wh, row_start, sorted_pack, out);
}